// Round 10
// baseline (128.097 us; speedup 1.0000x reference)
//
#include <hip/hip_runtime.h>

#define NB 32
#define NN 2048
#define ND 128
#define NSUP 2032
#define KKEEP 1016
#define MM 1032

typedef unsigned long long u64;
typedef unsigned int u32;

// Opaque IEEE f32 RN ops — compiler cannot contract/reassociate these.
__device__ __forceinline__ float mulrn(float a, float b) {
  float r;
  asm("v_mul_f32 %0, %1, %2" : "=v"(r) : "v"(a), "v"(b));
  return r;
}
__device__ __forceinline__ float addrn(float a, float b) {
  float r;
  asm("v_add_f32 %0, %1, %2" : "=v"(r) : "v"(a), "v"(b));
  return r;
}
// Single-rounded FMA — matches x86 vfmadd exactly.
__device__ __forceinline__ float fmarn(float a, float b, float c) {
  float r;
  asm("v_fma_f32 %0, %1, %2, %3" : "=v"(r) : "v"(a), "v"(b), "v"(c));
  return r;
}

// ---------------------------------------------------------------------------
// K1: one thread per (b,n) row. Emulates the JAX/XLA-CPU f32 pipeline:
//
//  dot (XLA RowMajorMatrixVectorProductEmitter, W=16 zmm, NO fast-math):
//    ONE <16 x float> accumulator, lane k <- d = k, k+16, ..., k+112,
//    8 sequential steps of SEPARATE fmul + fadd (VectorSupportLibrary::
//    MulAdd emits Add(Mul(a,b),c); fast-math off -> LLVM does NOT contract
//    to FMA). Then VSL AddReduce shuffle-halving tree:
//    l[k]+=l[k+8]; l[k]+=l[k+4]; l[k]+=l[k+2]; dot=l0+l1.
//
//  z = (dot + b[0]) / 100.0f — CR f32 div.
//
//  sigmoid (logistic_expander): 1/(1+exp(-z)); XLA/Eigen pexp f32 in the
//    m=0 regime (|x|<=0.06): Cephes Horner p0..p5, y=y*z2+x, e=y+1.
//    (fused-vs-separate here is provably negligible: delta ~1e-11 vs
//    e's ulp 1.2e-7.)
//
//  KEY = f32 SCORE bits (quantized -> ref's ulp-ties preserved) | row index
//  (stable tie-break = lower index first, matching stable lax.top_k).
// ---------------------------------------------------------------------------
__global__ __launch_bounds__(256) void k_score(const float* __restrict__ X,
                                               const float* __restrict__ w,
                                               const float* __restrict__ bias,
                                               u64* __restrict__ keys,
                                               float* __restrict__ score) {
#pragma clang fp contract(off)
  int row = blockIdx.x * 256 + threadIdx.x;
  if (row >= NB * NN) return;
  const float* x = X + (size_t)row * ND;

  // ---- W16 single-accumulator chain, SEPARATE mul/add ----
  float l[16];
  #pragma unroll
  for (int k = 0; k < 16; ++k) l[k] = 0.f;
  #pragma unroll
  for (int step = 0; step < 8; ++step) {
    const float* xp = x + step * 16;
    const float* wp = w + step * 16;
    #pragma unroll
    for (int q4 = 0; q4 < 4; ++q4) {
      const float4 xv = *reinterpret_cast<const float4*>(xp + q4 * 4);
      const float4 wv = *reinterpret_cast<const float4*>(wp + q4 * 4);
      l[q4 * 4 + 0] = addrn(mulrn(xv.x, wv.x), l[q4 * 4 + 0]);
      l[q4 * 4 + 1] = addrn(mulrn(xv.y, wv.y), l[q4 * 4 + 1]);
      l[q4 * 4 + 2] = addrn(mulrn(xv.z, wv.z), l[q4 * 4 + 2]);
      l[q4 * 4 + 3] = addrn(mulrn(xv.w, wv.w), l[q4 * 4 + 3]);
    }
  }
  // VSL AddReduce halving tree: 16 -> 8 -> 4 -> 2 -> 1
  #pragma unroll
  for (int k = 0; k < 8; ++k) l[k] = addrn(l[k], l[k + 8]);
  #pragma unroll
  for (int k = 0; k < 4; ++k) l[k] = addrn(l[k], l[k + 4]);
  l[0] = addrn(l[0], l[2]);
  l[1] = addrn(l[1], l[3]);
  const float dot = addrn(l[0], l[1]);

  // ---- z = (dot + b)/100, CR f32 ----
  const float z = __fdiv_rn(addrn(dot, bias[0]), 100.0f);

  // ---- XLA/Eigen pexp f32, m=0 regime, Cephes Horner ----
  const float xe = -z;
  const float z2 = mulrn(xe, xe);
  float y = fmarn(1.9875691500E-4f, xe, 1.3981999507E-3f);
  y = fmarn(y, xe, 8.3334519073E-3f);
  y = fmarn(y, xe, 4.1665795894E-2f);
  y = fmarn(y, xe, 1.6666665459E-1f);
  y = fmarn(y, xe, 5.0000001201E-1f);
  y = fmarn(y, z2, xe);
  const float e = addrn(y, 1.0f);

  // ---- sigmoid = 1/(1+e), CR f32 div ----
  const float s = __fdiv_rn(1.0f, addrn(1.0f, e));

  score[row] = s;

  // s > 0 always -> positive-float bits are ascending-sortable directly
  const u32 sb = __float_as_uint(s);
  const int n = row & (NN - 1);                    // index within batch
  keys[row] = ((u64)sb << 32) | (u32)n;
}

// ---------------------------------------------------------------------------
// K2: one block per batch. Bitonic sort of 2048 u64 keys (score-bits | idx)
//     in LDS; 16 pads = u64::MAX. Equal f32 scores (ref ties) order by index,
//     matching stable lax.top_k. First 1016 = support selection order.
// ---------------------------------------------------------------------------
__global__ __launch_bounds__(1024) void k_sort(const u64* __restrict__ keys,
                                               const float* __restrict__ score,
                                               int* __restrict__ idxs,
                                               float* __restrict__ vals,
                                               float* __restrict__ out_idx) {
  __shared__ u64 sk[NN];   // 16 KiB
  int b = blockIdx.x, t = threadIdx.x;
  for (int i = t; i < NN; i += 1024)
    sk[i] = (i < NSUP) ? keys[(size_t)b * NN + i] : ~0ull;
  __syncthreads();
  for (int k = 2; k <= NN; k <<= 1) {
    for (int j = k >> 1; j > 0; j >>= 1) {
      int i = ((t / j) * (j << 1)) + (t % j);
      int p = i + j;
      bool up = ((i & k) == 0);
      u64 ki = sk[i], kp = sk[p];
      if ((ki > kp) == up) { sk[i] = kp; sk[p] = ki; }
      __syncthreads();
    }
  }
  for (int i = t; i < MM; i += 1024) {
    int si = (i < KKEEP) ? (int)(sk[i] & 0xffffffffu) : (NSUP + (i - KKEEP));
    idxs[b * MM + i]    = si;
    vals[b * MM + i]    = score[(size_t)b * NN + si];
    out_idx[b * MM + i] = (float)si;
  }
}

// ---------------------------------------------------------------------------
// K3: one wave per output row: new_X[b,i,:] = X[b, idx, :] * value
// ---------------------------------------------------------------------------
__global__ __launch_bounds__(256) void k_newx(const float* __restrict__ X,
                                              const int* __restrict__ idxs,
                                              const float* __restrict__ vals,
                                              float* __restrict__ out_x) {
  int gid  = blockIdx.x * blockDim.x + threadIdx.x;
  int row  = gid >> 6;
  int lane = threadIdx.x & 63;
  if (row >= NB * MM) return;
  int b  = row / MM;
  int ri = idxs[row];
  float v = vals[row];
  const float2 x2 = *reinterpret_cast<const float2*>(X + ((size_t)b * NN + ri) * ND + lane * 2);
  float2 o = make_float2(x2.x * v, x2.y * v);
  *reinterpret_cast<float2*>(out_x + (size_t)row * ND + lane * 2) = o;
}

// ---------------------------------------------------------------------------
// K4: one block per output row: new_A[b,i,j] = A[b, idx[i], idx[j]].
//     Scattered reads stay inside one 8 KiB A-row (L1-resident); stores are
//     float4-coalesced. Carries ~90% of HBM traffic (~270 MB rd + 136 MB wr).
// ---------------------------------------------------------------------------
__global__ __launch_bounds__(256) void k_newa(const float* __restrict__ A,
                                              const int* __restrict__ idxs,
                                              float* __restrict__ out_a) {
  int row = blockIdx.x;                 // 0 .. NB*MM-1
  int b   = row / MM;
  const float* arow = A + ((size_t)b * NN + idxs[row]) * NN;
  const int* cols   = idxs + b * MM;
  float4* orow = reinterpret_cast<float4*>(out_a + (size_t)row * MM);
  for (int c = threadIdx.x; c < MM / 4; c += 256) {
    const int4 j4 = *reinterpret_cast<const int4*>(cols + c * 4);
    float4 o;
    o.x = arow[j4.x];
    o.y = arow[j4.y];
    o.z = arow[j4.z];
    o.w = arow[j4.w];
    orow[c] = o;
  }
}

extern "C" void kernel_launch(void* const* d_in, const int* in_sizes, int n_in,
                              void* d_out, int out_size, void* d_ws, size_t ws_size,
                              hipStream_t stream) {
  const float* A    = (const float*)d_in[0];   // [32,2048,2048]
  const float* X    = (const float*)d_in[1];   // [32,2048,128]
  const float* w    = (const float*)d_in[2];   // [128]
  const float* bias = (const float*)d_in[3];   // [1]

  float* out0 = (float*)d_out;                          // new_A
  float* out1 = out0 + (size_t)NB * MM * MM;            // new_X
  float* out2 = out1 + (size_t)NB * MM * ND;            // idx (as f32)

  u64*   keys  = (u64*)d_ws;                 // [32][2048] u64
  float* score = (float*)(keys + NB * NN);   // [32][2048] f32
  int*   idxs  = (int*)(score + NB * NN);    // [32][1032] i32
  float* vals  = (float*)(idxs + NB * MM);   // [32][1032] f32

  hipLaunchKernelGGL(k_score, dim3(NB * NN / 256), dim3(256), 0, stream, X, w, bias, keys, score);
  hipLaunchKernelGGL(k_sort,  dim3(NB),            dim3(1024), 0, stream, keys, score, idxs, vals, out2);
  hipLaunchKernelGGL(k_newx,  dim3(NB * MM / 4),   dim3(256), 0, stream, X, idxs, vals, out1);
  hipLaunchKernelGGL(k_newa,  dim3(NB * MM),       dim3(256), 0, stream, A, idxs, out0);
}

// Round 11
// 127.259 us; speedup vs baseline: 1.0066x; 1.0066x over previous
//
#include <hip/hip_runtime.h>

#define NB 32
#define NN 2048
#define ND 128
#define NSUP 2032
#define KKEEP 1016
#define MM 1032

typedef unsigned long long u64;
typedef unsigned int u32;

// Opaque IEEE f32 RN ops — compiler cannot contract/reassociate these.
__device__ __forceinline__ float mulrn(float a, float b) {
  float r;
  asm("v_mul_f32 %0, %1, %2" : "=v"(r) : "v"(a), "v"(b));
  return r;
}
__device__ __forceinline__ float addrn(float a, float b) {
  float r;
  asm("v_add_f32 %0, %1, %2" : "=v"(r) : "v"(a), "v"(b));
  return r;
}
// Single-rounded FMA — matches x86 vfmadd exactly.
__device__ __forceinline__ float fmarn(float a, float b, float c) {
  float r;
  asm("v_fma_f32 %0, %1, %2, %3" : "=v"(r) : "v"(a), "v"(b), "v"(c));
  return r;
}

// ---------------------------------------------------------------------------
// K1: bit-exact JAX/XLA-CPU f32 score (VERIFIED round 10 — do not change):
//   W16 single-accumulator chain with SEPARATE mul/add, halving-tree reduce,
//   CR f32 div by 100, Eigen/Cephes pexp Horner (m=0 regime), 1/(1+e) CR div.
//   KEY = f32 score bits (ref's ulp-ties preserved) | row idx (stable ties).
// ---------------------------------------------------------------------------
__global__ __launch_bounds__(256) void k_score(const float* __restrict__ X,
                                               const float* __restrict__ w,
                                               const float* __restrict__ bias,
                                               u64* __restrict__ keys,
                                               float* __restrict__ score) {
#pragma clang fp contract(off)
  int row = blockIdx.x * 256 + threadIdx.x;
  if (row >= NB * NN) return;
  const float* x = X + (size_t)row * ND;

  // ---- W16 single-accumulator chain, SEPARATE mul/add ----
  float l[16];
  #pragma unroll
  for (int k = 0; k < 16; ++k) l[k] = 0.f;
  #pragma unroll
  for (int step = 0; step < 8; ++step) {
    const float* xp = x + step * 16;
    const float* wp = w + step * 16;
    #pragma unroll
    for (int q4 = 0; q4 < 4; ++q4) {
      const float4 xv = *reinterpret_cast<const float4*>(xp + q4 * 4);
      const float4 wv = *reinterpret_cast<const float4*>(wp + q4 * 4);
      l[q4 * 4 + 0] = addrn(mulrn(xv.x, wv.x), l[q4 * 4 + 0]);
      l[q4 * 4 + 1] = addrn(mulrn(xv.y, wv.y), l[q4 * 4 + 1]);
      l[q4 * 4 + 2] = addrn(mulrn(xv.z, wv.z), l[q4 * 4 + 2]);
      l[q4 * 4 + 3] = addrn(mulrn(xv.w, wv.w), l[q4 * 4 + 3]);
    }
  }
  // halving tree: 16 -> 8 -> 4 -> 2 -> 1
  #pragma unroll
  for (int k = 0; k < 8; ++k) l[k] = addrn(l[k], l[k + 8]);
  #pragma unroll
  for (int k = 0; k < 4; ++k) l[k] = addrn(l[k], l[k + 4]);
  l[0] = addrn(l[0], l[2]);
  l[1] = addrn(l[1], l[3]);
  const float dot = addrn(l[0], l[1]);

  // ---- z = (dot + b)/100, CR f32 ----
  const float z = __fdiv_rn(addrn(dot, bias[0]), 100.0f);

  // ---- Eigen/Cephes pexp f32, m=0 regime, Horner ----
  const float xe = -z;
  const float z2 = mulrn(xe, xe);
  float y = fmarn(1.9875691500E-4f, xe, 1.3981999507E-3f);
  y = fmarn(y, xe, 8.3334519073E-3f);
  y = fmarn(y, xe, 4.1665795894E-2f);
  y = fmarn(y, xe, 1.6666665459E-1f);
  y = fmarn(y, xe, 5.0000001201E-1f);
  y = fmarn(y, z2, xe);
  const float e = addrn(y, 1.0f);

  // ---- sigmoid = 1/(1+e), CR f32 div ----
  const float s = __fdiv_rn(1.0f, addrn(1.0f, e));

  score[row] = s;

  const u32 sb = __float_as_uint(s);   // s>0 -> bits ascending-sortable
  const int n = row & (NN - 1);
  keys[row] = ((u64)sb << 32) | (u32)n;
}

// ---------------------------------------------------------------------------
// K2: one block per batch. Bitonic sort of 2048 u64 keys (score-bits | idx)
//     in LDS; 16 pads = u64::MAX. Equal scores order by index (stable top_k).
// ---------------------------------------------------------------------------
__global__ __launch_bounds__(1024) void k_sort(const u64* __restrict__ keys,
                                               const float* __restrict__ score,
                                               int* __restrict__ idxs,
                                               float* __restrict__ vals,
                                               float* __restrict__ out_idx) {
  __shared__ u64 sk[NN];   // 16 KiB
  int b = blockIdx.x, t = threadIdx.x;
  for (int i = t; i < NN; i += 1024)
    sk[i] = (i < NSUP) ? keys[(size_t)b * NN + i] : ~0ull;
  __syncthreads();
  for (int k = 2; k <= NN; k <<= 1) {
    for (int j = k >> 1; j > 0; j >>= 1) {
      int i = ((t / j) * (j << 1)) + (t % j);
      int p = i + j;
      bool up = ((i & k) == 0);
      u64 ki = sk[i], kp = sk[p];
      if ((ki > kp) == up) { sk[i] = kp; sk[p] = ki; }
      __syncthreads();
    }
  }
  for (int i = t; i < MM; i += 1024) {
    int si = (i < KKEEP) ? (int)(sk[i] & 0xffffffffu) : (NSUP + (i - KKEEP));
    idxs[b * MM + i]    = si;
    vals[b * MM + i]    = score[(size_t)b * NN + si];
    out_idx[b * MM + i] = (float)si;
  }
}

// ---------------------------------------------------------------------------
// K3: one wave per output row: new_X[b,i,:] = X[b, idx, :] * value
// ---------------------------------------------------------------------------
__global__ __launch_bounds__(256) void k_newx(const float* __restrict__ X,
                                              const int* __restrict__ idxs,
                                              const float* __restrict__ vals,
                                              float* __restrict__ out_x) {
  int gid  = blockIdx.x * blockDim.x + threadIdx.x;
  int row  = gid >> 6;
  int lane = threadIdx.x & 63;
  if (row >= NB * MM) return;
  int b  = row / MM;
  int ri = idxs[row];
  float v = vals[row];
  const float2 x2 = *reinterpret_cast<const float2*>(X + ((size_t)b * NN + ri) * ND + lane * 2);
  float2 o = make_float2(x2.x * v, x2.y * v);
  *reinterpret_cast<float2*>(out_x + (size_t)row * ND + lane * 2) = o;
}

// ---------------------------------------------------------------------------
// K4: one block per output row: new_A[b,i,j] = A[b, idx[i], idx[j]].
//     v2: stage the 8 KiB A-row into LDS with coalesced float4 loads, then
//     gather from LDS (random idx -> ~2-way bank aliasing, free per m136).
//     Converts 1032 scattered global dword loads/block (address-divergence
//     bound in the TA) into 512 coalesced float4 loads + LDS scatter.
//     HBM traffic unchanged (~270 MB rd + 136 MB wr); removes the TA stall.
// ---------------------------------------------------------------------------
__global__ __launch_bounds__(256) void k_newa(const float* __restrict__ A,
                                              const int* __restrict__ idxs,
                                              float* __restrict__ out_a) {
  __shared__ float srow[NN];     // 8 KiB
  __shared__ int   scols[MM];    // ~4 KiB
  int row = blockIdx.x;                 // 0 .. NB*MM-1
  int b   = row / MM;
  const int* cols = idxs + b * MM;
  for (int i = threadIdx.x; i < MM; i += 256) scols[i] = cols[i];

  int ri = idxs[row];                   // uniform per block
  const float* arow = A + ((size_t)b * NN + ri) * NN;
  #pragma unroll
  for (int i = 0; i < 2; ++i) {         // 2048 floats = 512 float4, 2/thread
    int off = (threadIdx.x + i * 256) * 4;
    *reinterpret_cast<float4*>(&srow[off]) =
        *reinterpret_cast<const float4*>(arow + off);
  }
  __syncthreads();

  float4* orow = reinterpret_cast<float4*>(out_a + (size_t)row * MM);
  for (int c = threadIdx.x; c < MM / 4; c += 256) {
    const int4 j4 = *reinterpret_cast<const int4*>(scols + c * 4);
    float4 o;
    o.x = srow[j4.x];
    o.y = srow[j4.y];
    o.z = srow[j4.z];
    o.w = srow[j4.w];
    orow[c] = o;
  }
}

extern "C" void kernel_launch(void* const* d_in, const int* in_sizes, int n_in,
                              void* d_out, int out_size, void* d_ws, size_t ws_size,
                              hipStream_t stream) {
  const float* A    = (const float*)d_in[0];   // [32,2048,2048]
  const float* X    = (const float*)d_in[1];   // [32,2048,128]
  const float* w    = (const float*)d_in[2];   // [128]
  const float* bias = (const float*)d_in[3];   // [1]

  float* out0 = (float*)d_out;                          // new_A
  float* out1 = out0 + (size_t)NB * MM * MM;            // new_X
  float* out2 = out1 + (size_t)NB * MM * ND;            // idx (as f32)

  u64*   keys  = (u64*)d_ws;                 // [32][2048] u64
  float* score = (float*)(keys + NB * NN);   // [32][2048] f32
  int*   idxs  = (int*)(score + NB * NN);    // [32][1032] i32
  float* vals  = (float*)(idxs + NB * MM);   // [32][1032] f32

  hipLaunchKernelGGL(k_score, dim3(NB * NN / 256), dim3(256), 0, stream, X, w, bias, keys, score);
  hipLaunchKernelGGL(k_sort,  dim3(NB),            dim3(1024), 0, stream, keys, score, idxs, vals, out2);
  hipLaunchKernelGGL(k_newx,  dim3(NB * MM / 4),   dim3(256), 0, stream, X, idxs, vals, out1);
  hipLaunchKernelGGL(k_newa,  dim3(NB * MM),       dim3(256), 0, stream, A, idxs, out0);
}

// Round 12
// 117.368 us; speedup vs baseline: 1.0914x; 1.0843x over previous
//
#include <hip/hip_runtime.h>

#define NB 32
#define NN 2048
#define ND 128
#define NSUP 2032
#define KKEEP 1016
#define MM 1032

typedef unsigned long long u64;
typedef unsigned int u32;

// Opaque IEEE f32 RN ops — compiler cannot contract/reassociate these.
__device__ __forceinline__ float mulrn(float a, float b) {
  float r;
  asm("v_mul_f32 %0, %1, %2" : "=v"(r) : "v"(a), "v"(b));
  return r;
}
__device__ __forceinline__ float addrn(float a, float b) {
  float r;
  asm("v_add_f32 %0, %1, %2" : "=v"(r) : "v"(a), "v"(b));
  return r;
}
// Single-rounded FMA — matches x86 vfmadd exactly.
__device__ __forceinline__ float fmarn(float a, float b, float c) {
  float r;
  asm("v_fma_f32 %0, %1, %2, %3" : "=v"(r) : "v"(a), "v"(b), "v"(c));
  return r;
}

// ---------------------------------------------------------------------------
// K1: bit-exact JAX/XLA-CPU f32 score (VERIFIED round 10 — do not change):
//   W16 single-accumulator chain with SEPARATE mul/add, halving-tree reduce,
//   CR f32 div by 100, Eigen/Cephes pexp Horner (m=0 regime), 1/(1+e) CR div.
//   KEY = f32 score bits (ref's ulp-ties preserved) | row idx (stable ties).
// ---------------------------------------------------------------------------
__global__ __launch_bounds__(256) void k_score(const float* __restrict__ X,
                                               const float* __restrict__ w,
                                               const float* __restrict__ bias,
                                               u64* __restrict__ keys,
                                               float* __restrict__ score) {
#pragma clang fp contract(off)
  int row = blockIdx.x * 256 + threadIdx.x;
  if (row >= NB * NN) return;
  const float* x = X + (size_t)row * ND;

  float l[16];
  #pragma unroll
  for (int k = 0; k < 16; ++k) l[k] = 0.f;
  #pragma unroll
  for (int step = 0; step < 8; ++step) {
    const float* xp = x + step * 16;
    const float* wp = w + step * 16;
    #pragma unroll
    for (int q4 = 0; q4 < 4; ++q4) {
      const float4 xv = *reinterpret_cast<const float4*>(xp + q4 * 4);
      const float4 wv = *reinterpret_cast<const float4*>(wp + q4 * 4);
      l[q4 * 4 + 0] = addrn(mulrn(xv.x, wv.x), l[q4 * 4 + 0]);
      l[q4 * 4 + 1] = addrn(mulrn(xv.y, wv.y), l[q4 * 4 + 1]);
      l[q4 * 4 + 2] = addrn(mulrn(xv.z, wv.z), l[q4 * 4 + 2]);
      l[q4 * 4 + 3] = addrn(mulrn(xv.w, wv.w), l[q4 * 4 + 3]);
    }
  }
  #pragma unroll
  for (int k = 0; k < 8; ++k) l[k] = addrn(l[k], l[k + 8]);
  #pragma unroll
  for (int k = 0; k < 4; ++k) l[k] = addrn(l[k], l[k + 4]);
  l[0] = addrn(l[0], l[2]);
  l[1] = addrn(l[1], l[3]);
  const float dot = addrn(l[0], l[1]);

  const float z = __fdiv_rn(addrn(dot, bias[0]), 100.0f);

  const float xe = -z;
  const float z2 = mulrn(xe, xe);
  float y = fmarn(1.9875691500E-4f, xe, 1.3981999507E-3f);
  y = fmarn(y, xe, 8.3334519073E-3f);
  y = fmarn(y, xe, 4.1665795894E-2f);
  y = fmarn(y, xe, 1.6666665459E-1f);
  y = fmarn(y, xe, 5.0000001201E-1f);
  y = fmarn(y, z2, xe);
  const float e = addrn(y, 1.0f);

  const float s = __fdiv_rn(1.0f, addrn(1.0f, e));

  score[row] = s;

  const u32 sb = __float_as_uint(s);   // s>0 -> bits ascending-sortable
  const int n = row & (NN - 1);
  keys[row] = ((u64)sb << 32) | (u32)n;
}

// Register compare-exchange for the XOR bitonic network: pair {e, e^j},
// up = ((e&k)==0); the lower element keeps min when ascending. Identical
// pairs/predicates to the verified LDS formulation (keys are distinct).
__device__ __forceinline__ u64 cmpex(u64 v, int j, bool up, int l) {
  u64 o = __shfl_xor(v, j, 64);
  bool lower = ((l & j) == 0);
  u64 mn = (v < o) ? v : o;
  u64 mx = (v < o) ? o : v;
  return (lower == up) ? mn : mx;
}

// ---------------------------------------------------------------------------
// K2 v2: hybrid register/LDS bitonic. All j<=32 stages stay inside
//   64-element blocks -> done in registers via shfl_xor (2 elems/lane,
//   barrier-free). Only j>=64 stages go through LDS. Barriers: 66 -> 21.
// ---------------------------------------------------------------------------
__global__ __launch_bounds__(1024) void k_sort(const u64* __restrict__ keys,
                                               const float* __restrict__ score,
                                               int* __restrict__ idxs,
                                               float* __restrict__ vals,
                                               float* __restrict__ out_idx) {
  __shared__ u64 sk[NN];   // 16 KiB
  const int b = blockIdx.x, t = threadIdx.x;
  const int l = t & 63;
  const int base0 = (t >> 6) * 128;        // wave's first 64-block
  const size_t bNN = (size_t)b * NN;

  // load 2 elements/thread straight into registers (coalesced u64 reads)
  u64 v0 = (base0 + l      < NSUP) ? keys[bNN + base0 + l]      : ~0ull;
  u64 v1 = (base0 + 64 + l < NSUP) ? keys[bNN + base0 + 64 + l] : ~0ull;

  // k = 2..32: up depends on lane only (base0 % 64 == 0, k <= 32)
  #pragma unroll
  for (int k = 2; k <= 32; k <<= 1) {
    #pragma unroll
    for (int j = k >> 1; j >= 1; j >>= 1) {
      bool up = ((l & k) == 0);
      v0 = cmpex(v0, j, up, l);
      v1 = cmpex(v1, j, up, l);
    }
  }
  // k = 64: block0 ascending (bit6 of base0+l is 0), block1 descending
  #pragma unroll
  for (int j = 32; j >= 1; j >>= 1) {
    v0 = cmpex(v0, j, true, l);
    v1 = cmpex(v1, j, false, l);
  }
  sk[base0 + l]      = v0;
  sk[base0 + 64 + l] = v1;
  __syncthreads();

  // k = 128..2048
  for (int k = 128; k <= NN; k <<= 1) {
    for (int j = k >> 1; j >= 64; j >>= 1) {        // LDS stages
      int i = ((t / j) * (j << 1)) + (t % j);
      int p = i + j;
      bool up = ((i & k) == 0);
      u64 a = sk[i], c = sk[p];
      if ((a > c) == up) { sk[i] = c; sk[p] = a; }
      __syncthreads();
    }
    // j = 32..1 in registers; up uniform per 64-block (k >= 128)
    bool up0 = ((base0 & k) == 0);
    v0 = sk[base0 + l];
    v1 = sk[base0 + 64 + l];
    #pragma unroll
    for (int j = 32; j >= 1; j >>= 1) {
      v0 = cmpex(v0, j, up0, l);
      v1 = cmpex(v1, j, up0, l);
    }
    sk[base0 + l]      = v0;
    sk[base0 + 64 + l] = v1;
    __syncthreads();
  }

  for (int i = t; i < MM; i += 1024) {
    int si = (i < KKEEP) ? (int)(sk[i] & 0xffffffffu) : (NSUP + (i - KKEEP));
    idxs[b * MM + i]    = si;
    vals[b * MM + i]    = score[bNN + si];
    out_idx[b * MM + i] = (float)si;
  }
}

// ---------------------------------------------------------------------------
// K4 (fused): one block per output row.
//   new_A[b,i,j] = A[b, idx[i], idx[j]]  (LDS-staged row gather)
//   new_X[b,i,:] = X[b, idx[i], :] * val[i]  (first 32 lanes, hidden under A)
// ---------------------------------------------------------------------------
__global__ __launch_bounds__(256) void k_newa(const float* __restrict__ A,
                                              const float* __restrict__ X,
                                              const int* __restrict__ idxs,
                                              const float* __restrict__ vals,
                                              float* __restrict__ out_a,
                                              float* __restrict__ out_x) {
  __shared__ float srow[NN];     // 8 KiB
  __shared__ int   scols[MM];    // ~4 KiB
  int row = blockIdx.x;                 // 0 .. NB*MM-1
  int b   = row / MM;
  const int* cols = idxs + b * MM;
  for (int i = threadIdx.x; i < MM; i += 256) scols[i] = cols[i];

  int ri = idxs[row];                   // uniform per block
  const float* arow = A + ((size_t)b * NN + ri) * NN;
  #pragma unroll
  for (int i = 0; i < 2; ++i) {         // 2048 floats = 512 float4, 2/thread
    int off = (threadIdx.x + i * 256) * 4;
    *reinterpret_cast<float4*>(&srow[off]) =
        *reinterpret_cast<const float4*>(arow + off);
  }

  // fused new_X: 32 lanes x float4 = 128 floats
  if (threadIdx.x < 32) {
    float v = vals[row];
    const float4 xv = reinterpret_cast<const float4*>(
        X + ((size_t)b * NN + ri) * ND)[threadIdx.x];
    float4 o = make_float4(xv.x * v, xv.y * v, xv.z * v, xv.w * v);
    reinterpret_cast<float4*>(out_x + (size_t)row * ND)[threadIdx.x] = o;
  }
  __syncthreads();

  float4* orow = reinterpret_cast<float4*>(out_a + (size_t)row * MM);
  for (int c = threadIdx.x; c < MM / 4; c += 256) {
    const int4 j4 = *reinterpret_cast<const int4*>(scols + c * 4);
    float4 o;
    o.x = srow[j4.x];
    o.y = srow[j4.y];
    o.z = srow[j4.z];
    o.w = srow[j4.w];
    orow[c] = o;
  }
}

extern "C" void kernel_launch(void* const* d_in, const int* in_sizes, int n_in,
                              void* d_out, int out_size, void* d_ws, size_t ws_size,
                              hipStream_t stream) {
  const float* A    = (const float*)d_in[0];   // [32,2048,2048]
  const float* X    = (const float*)d_in[1];   // [32,2048,128]
  const float* w    = (const float*)d_in[2];   // [128]
  const float* bias = (const float*)d_in[3];   // [1]

  float* out0 = (float*)d_out;                          // new_A
  float* out1 = out0 + (size_t)NB * MM * MM;            // new_X
  float* out2 = out1 + (size_t)NB * MM * ND;            // idx (as f32)

  u64*   keys  = (u64*)d_ws;                 // [32][2048] u64
  float* score = (float*)(keys + NB * NN);   // [32][2048] f32
  int*   idxs  = (int*)(score + NB * NN);    // [32][1032] i32
  float* vals  = (float*)(idxs + NB * MM);   // [32][1032] f32

  hipLaunchKernelGGL(k_score, dim3(NB * NN / 256), dim3(256), 0, stream, X, w, bias, keys, score);
  hipLaunchKernelGGL(k_sort,  dim3(NB),            dim3(1024), 0, stream, keys, score, idxs, vals, out2);
  hipLaunchKernelGGL(k_newa,  dim3(NB * MM),       dim3(256), 0, stream, A, X, idxs, vals, out0, out1);
}

// Round 14
// 109.801 us; speedup vs baseline: 1.1666x; 1.0689x over previous
//
#include <hip/hip_runtime.h>

#define NB 32
#define NN 2048
#define ND 128
#define NSUP 2032
#define KKEEP 1016
#define MM 1032
#define SEG 254              // NSUP / 8 segments per batch

typedef unsigned long long u64;
typedef unsigned int u32;
typedef float f32x4 __attribute__((ext_vector_type(4)));   // clang-native vec4

// Opaque IEEE f32 RN ops — compiler cannot contract/reassociate these.
__device__ __forceinline__ float mulrn(float a, float b) {
  float r;
  asm("v_mul_f32 %0, %1, %2" : "=v"(r) : "v"(a), "v"(b));
  return r;
}
__device__ __forceinline__ float addrn(float a, float b) {
  float r;
  asm("v_add_f32 %0, %1, %2" : "=v"(r) : "v"(a), "v"(b));
  return r;
}
// Single-rounded FMA — matches x86 vfmadd exactly.
__device__ __forceinline__ float fmarn(float a, float b, float c) {
  float r;
  asm("v_fma_f32 %0, %1, %2, %3" : "=v"(r) : "v"(a), "v"(b), "v"(c));
  return r;
}

// ---------------------------------------------------------------------------
// K1: bit-exact JAX/XLA-CPU f32 score (VERIFIED round 10 — do not change):
//   W16 single-accumulator chain with SEPARATE mul/add, halving-tree reduce,
//   CR f32 div by 100, Eigen/Cephes pexp Horner (m=0 regime), 1/(1+e) CR div.
//   KEY = f32 score bits (ref's ulp-ties preserved) | row idx (stable ties).
// ---------------------------------------------------------------------------
__global__ __launch_bounds__(256) void k_score(const float* __restrict__ X,
                                               const float* __restrict__ w,
                                               const float* __restrict__ bias,
                                               u64* __restrict__ keys,
                                               float* __restrict__ score) {
#pragma clang fp contract(off)
  int row = blockIdx.x * 256 + threadIdx.x;
  if (row >= NB * NN) return;
  const float* x = X + (size_t)row * ND;

  float l[16];
  #pragma unroll
  for (int k = 0; k < 16; ++k) l[k] = 0.f;
  #pragma unroll
  for (int step = 0; step < 8; ++step) {
    const float* xp = x + step * 16;
    const float* wp = w + step * 16;
    #pragma unroll
    for (int q4 = 0; q4 < 4; ++q4) {
      const float4 xv = *reinterpret_cast<const float4*>(xp + q4 * 4);
      const float4 wv = *reinterpret_cast<const float4*>(wp + q4 * 4);
      l[q4 * 4 + 0] = addrn(mulrn(xv.x, wv.x), l[q4 * 4 + 0]);
      l[q4 * 4 + 1] = addrn(mulrn(xv.y, wv.y), l[q4 * 4 + 1]);
      l[q4 * 4 + 2] = addrn(mulrn(xv.z, wv.z), l[q4 * 4 + 2]);
      l[q4 * 4 + 3] = addrn(mulrn(xv.w, wv.w), l[q4 * 4 + 3]);
    }
  }
  #pragma unroll
  for (int k = 0; k < 8; ++k) l[k] = addrn(l[k], l[k + 8]);
  #pragma unroll
  for (int k = 0; k < 4; ++k) l[k] = addrn(l[k], l[k + 4]);
  l[0] = addrn(l[0], l[2]);
  l[1] = addrn(l[1], l[3]);
  const float dot = addrn(l[0], l[1]);

  const float z = __fdiv_rn(addrn(dot, bias[0]), 100.0f);

  const float xe = -z;
  const float z2 = mulrn(xe, xe);
  float y = fmarn(1.9875691500E-4f, xe, 1.3981999507E-3f);
  y = fmarn(y, xe, 8.3334519073E-3f);
  y = fmarn(y, xe, 4.1665795894E-2f);
  y = fmarn(y, xe, 1.6666665459E-1f);
  y = fmarn(y, xe, 5.0000001201E-1f);
  y = fmarn(y, z2, xe);
  const float e = addrn(y, 1.0f);

  const float s = __fdiv_rn(1.0f, addrn(1.0f, e));

  score[row] = s;

  const u32 sb = __float_as_uint(s);   // s>0 -> bits ascending-sortable
  const int n = row & (NN - 1);
  keys[row] = ((u64)sb << 32) | (u32)n;
}

// ---------------------------------------------------------------------------
// K2 v3: rank-by-counting selection (replaces bitonic sort; same total order:
//   (score_bits | idx) ascending, keys distinct). 8 blocks per batch, each
//   stages all 2032 support keys in LDS; each thread counts how many keys are
//   smaller than its element's -> rank == output position; rank < 1016 =
//   selected. Barrier-free scan, whole-machine parallel. Threads 254/255 of
//   each segment emit 2 query rows (8 segs x 2 = 16).
// ---------------------------------------------------------------------------
__global__ __launch_bounds__(256) void k_rank(const u64* __restrict__ keys,
                                              const float* __restrict__ score,
                                              int* __restrict__ idxs,
                                              float* __restrict__ vals,
                                              float* __restrict__ out_idx) {
  __shared__ u64 lk[NSUP];   // 16.3 KiB
  const int b   = blockIdx.x >> 3;
  const int seg = blockIdx.x & 7;
  const int t   = threadIdx.x;
  const size_t bNN = (size_t)b * NN;
  const int    bMM = b * MM;

  for (int i = t; i < NSUP; i += 256) lk[i] = keys[bNN + i];
  __syncthreads();

  if (t < SEG) {
    const int e  = seg * SEG + t;
    const u64 my = lk[e];
    int cnt = 0;
    #pragma unroll 4
    for (int s = 0; s < NSUP; s += 4) {
      const u64 k0 = lk[s], k1 = lk[s + 1], k2 = lk[s + 2], k3 = lk[s + 3];
      cnt += (int)(k0 < my) + (int)(k1 < my) + (int)(k2 < my) + (int)(k3 < my);
    }
    if (cnt < KKEEP) {
      idxs[bMM + cnt]    = e;
      vals[bMM + cnt]    = score[bNN + e];
      out_idx[bMM + cnt] = (float)e;
    }
  } else {
    const int q   = seg * 2 + (t - SEG);   // 0..15
    const int e   = NSUP + q;
    const int pos = KKEEP + q;
    idxs[bMM + pos]    = e;
    vals[bMM + pos]    = score[bNN + e];
    out_idx[bMM + pos] = (float)e;
  }
}

// ---------------------------------------------------------------------------
// K4 (fused): one 128-thread block per output row (13 blocks/CU -> more
//   outstanding HBM reads than the 256-thread/8-block config).
//   new_A[b,i,j] = A[b, idx[i], idx[j]]  (LDS-staged row, nontemporal IO)
//   new_X[b,i,:] = X[b, idx[i], :] * val[i]  (first 32 lanes)
// ---------------------------------------------------------------------------
__global__ __launch_bounds__(128) void k_newa(const float* __restrict__ A,
                                              const float* __restrict__ X,
                                              const int* __restrict__ idxs,
                                              const float* __restrict__ vals,
                                              float* __restrict__ out_a,
                                              float* __restrict__ out_x) {
  __shared__ float srow[NN];     // 8 KiB
  __shared__ int   scols[MM];    // ~4 KiB
  int row = blockIdx.x;                 // 0 .. NB*MM-1
  int b   = row / MM;
  const int* cols = idxs + b * MM;
  for (int c = threadIdx.x; c < MM / 4; c += 128)
    *reinterpret_cast<int4*>(&scols[c * 4]) =
        reinterpret_cast<const int4*>(cols)[c];

  int ri = idxs[row];                   // uniform per block
  const float* arow = A + ((size_t)b * NN + ri) * NN;
  #pragma unroll
  for (int i = 0; i < 4; ++i) {         // 2048 floats = 512 f32x4, 4/thread
    int off = (threadIdx.x + i * 128) * 4;
    *reinterpret_cast<f32x4*>(&srow[off]) =
        __builtin_nontemporal_load(reinterpret_cast<const f32x4*>(arow + off));
  }

  // fused new_X: 32 lanes x float4 = 128 floats
  if (threadIdx.x < 32) {
    float v = vals[row];
    const float4 xv = reinterpret_cast<const float4*>(
        X + ((size_t)b * NN + ri) * ND)[threadIdx.x];
    float4 o = make_float4(xv.x * v, xv.y * v, xv.z * v, xv.w * v);
    reinterpret_cast<float4*>(out_x + (size_t)row * ND)[threadIdx.x] = o;
  }
  __syncthreads();

  f32x4* orow = reinterpret_cast<f32x4*>(out_a + (size_t)row * MM);
  for (int c = threadIdx.x; c < MM / 4; c += 128) {
    const int4 j4 = *reinterpret_cast<const int4*>(scols + c * 4);
    f32x4 o;
    o.x = srow[j4.x];
    o.y = srow[j4.y];
    o.z = srow[j4.z];
    o.w = srow[j4.w];
    __builtin_nontemporal_store(o, orow + c);
  }
}

extern "C" void kernel_launch(void* const* d_in, const int* in_sizes, int n_in,
                              void* d_out, int out_size, void* d_ws, size_t ws_size,
                              hipStream_t stream) {
  const float* A    = (const float*)d_in[0];   // [32,2048,2048]
  const float* X    = (const float*)d_in[1];   // [32,2048,128]
  const float* w    = (const float*)d_in[2];   // [128]
  const float* bias = (const float*)d_in[3];   // [1]

  float* out0 = (float*)d_out;                          // new_A
  float* out1 = out0 + (size_t)NB * MM * MM;            // new_X
  float* out2 = out1 + (size_t)NB * MM * ND;            // idx (as f32)

  u64*   keys  = (u64*)d_ws;                 // [32][2048] u64
  float* score = (float*)(keys + NB * NN);   // [32][2048] f32
  int*   idxs  = (int*)(score + NB * NN);    // [32][1032] i32
  float* vals  = (float*)(idxs + NB * MM);   // [32][1032] f32

  hipLaunchKernelGGL(k_score, dim3(NB * NN / 256), dim3(256), 0, stream, X, w, bias, keys, score);
  hipLaunchKernelGGL(k_rank,  dim3(NB * 8),        dim3(256), 0, stream, keys, score, idxs, vals, out2);
  hipLaunchKernelGGL(k_newa,  dim3(NB * MM),       dim3(128), 0, stream, A, X, idxs, vals, out0, out1);
}